// Round 16
// baseline (539.320 us; speedup 1.0000x reference)
//
#include <hip/hip_runtime.h>
#include <hip/hip_bf16.h>

#define DIN 32
#define HC  64    // H*C
#define NPB 512   // nodes per bucket (dst >> 9)
#define CAP 18432 // fixed bucket capacity: E/NB=16384 expected, sigma~127 -> 16 sigma

using bf = __hip_bfloat16;
typedef float f2_t __attribute__((ext_vector_type(2)));
static __device__ __forceinline__ unsigned char f2fp8(float v){
  return (unsigned char)__builtin_amdgcn_cvt_pk_fp8_f32(v, v, 0, false);
}

// ---- fused: bucket-scatter (blocks < SB) || transform layer-1 ----------
// tf1: feat8A = fp8(x@W1) (gathered rows 64 B); asrc/adst from fp32 acc
// BEFORE quantization -> attention logits exact.

template<int K>
__global__ void k_scatter_tf(const int* __restrict__ edge, int E, int NB,
                             int* __restrict__ bcur, unsigned* __restrict__ buf,
                             int SB,
                             const float* __restrict__ xin,
                             const float* __restrict__ W,
                             const float* __restrict__ a_s,
                             const float* __restrict__ a_d,
                             unsigned char* __restrict__ feat8,
                             float* __restrict__ asrc, float* __restrict__ adst, int N,
                             int TB){
  __shared__ int lcnt[1024];
  __shared__ int lcur[1024];
  int t = threadIdx.x;
  if ((int)blockIdx.x < SB){               // ---- scatter half ----
    int chunk = (E + SB - 1) / SB;
    int beg = blockIdx.x*chunk, end = min(E, beg + chunk);
    for (int i = t; i < NB; i += blockDim.x) lcnt[i] = 0;
    __syncthreads();
    for (int i = beg + t; i < end; i += blockDim.x)
      atomicAdd(&lcnt[edge[E + i] >> 9], 1);
    __syncthreads();
    for (int i = t; i < NB; i += blockDim.x){
      int c = lcnt[i];
      lcur[i] = i*CAP + (c ? atomicAdd(&bcur[i], c) : 0);
    }
    __syncthreads();
    for (int i = beg + t; i < end; i += blockDim.x){
      int sN = edge[i], d = edge[E + i];
      int pos = atomicAdd(&lcur[d >> 9], 1);
      buf[pos] = ((unsigned)sN << 9) | (unsigned)(d & 511);
    }
    return;
  }
  // ---- transform half (W column in VGPRs, x same-addr broadcast)
  int lane = t & 63, wid = t >> 6;
  float wreg[K];
  #pragma unroll
  for (int k = 0; k < K; k++) wreg[k] = W[k*HC + lane];
  float as_l = a_s[lane], ad_l = a_d[lane];
  int gw = (blockIdx.x - SB)*4 + wid;
  int nw = TB*4;
  for (int n = gw; n < N; n += nw){
    float acc = 0.f;
    const float* xr = xin + (size_t)n*K;
    #pragma unroll
    for (int k = 0; k < K; k += 4){
      float4 xv = *(const float4*)(xr + k);              // same-addr broadcast
      acc = fmaf(xv.x, wreg[k+0], acc);
      acc = fmaf(xv.y, wreg[k+1], acc);
      acc = fmaf(xv.z, wreg[k+2], acc);
      acc = fmaf(xv.w, wreg[k+3], acc);
    }
    feat8[((size_t)n << 6) + lane] = f2fp8(acc);         // 1 B/lane, 64 B row
    float ps = acc*as_l, pd = acc*ad_l;                  // fp32: logits exact
    #pragma unroll
    for (int d = 1; d < 16; d <<= 1){ ps += __shfl_xor(ps, d); pd += __shfl_xor(pd, d); }
    if ((lane & 15) == 0){
      asrc[n*4 + (lane>>4)] = ps;
      adst[n*4 + (lane>>4)] = pd;
    }
  }
}

// one block (512 thr) per bucket: self-scan of bucket fills (folded bscan),
// then local CSR in LDS; self-loop slot 0.
__global__ void k_bbuild(const unsigned* __restrict__ buf, const int* __restrict__ bcur,
                         const int* __restrict__ batch,
                         int NB, int N, int* __restrict__ offs, int* __restrict__ srcs,
                         int* __restrict__ gcnt){
  __shared__ int s[NPB];
  __shared__ int cur[NPB];
  int b = blockIdx.x, t = threadIdx.x;
  // ---- integrated exclusive scan of bucket fills -> sb ----
  cur[t] = (t < NB) ? min(bcur[t], CAP) : 0;
  __syncthreads();
  for (int d = 1; d < NPB; d <<= 1){
    int v = (t >= d) ? cur[t-d] : 0;
    __syncthreads();
    cur[t] += v;
    __syncthreads();
  }
  int sb = ((b > 0) ? cur[b-1] : 0) + b*NPB;   // + self-loops of prior buckets
  if (b == 0 && t == 0) offs[N] = cur[NB-1] + N;
  __syncthreads();                              // cur reused below
  // ---- local CSR ----
  int base = b << 9;
  int nn = min(NPB, N - base);
  int sbeg = b*CAP;
  int send = sbeg + min(bcur[b], CAP);
  s[t] = (t < nn) ? 1 : 0;                 // self-loop seed
  __syncthreads();
  for (int i = sbeg + t; i < send; i += NPB)
    atomicAdd(&s[buf[i] & 511u], 1);
  __syncthreads();
  int c0 = s[t];
  __syncthreads();
  for (int d = 1; d < NPB; d <<= 1){
    int v = (t >= d) ? s[t-d] : 0;
    __syncthreads();
    s[t] += v;
    __syncthreads();
  }
  int start = s[t] - c0;
  if (t < nn){
    offs[base + t] = sb + start;
    srcs[sb + start] = base + t;           // self-loop
    cur[t] = start + 1;
    atomicAdd(&gcnt[batch[base + t]], 1);  // graph node count
  }
  __syncthreads();
  for (int i = sbeg + t; i < send; i += NPB){
    unsigned v = buf[i];
    int pos = atomicAdd(&cur[v & 511u], 1);
    srcs[sb + pos] = (int)(v >> 9);
  }
}

// ---- layer-1 aggregate + FUSED layer-2 transform, GRID-STRIDE ----------
// R15 post-mortem: 25k blocks each staging 16 KB W2 = 400 MB L2 traffic +
// per-4-nodes sync -> 189 us (the R7 staging-amortization lesson again).
// Fix: 1536 blocks (= 256 CU x 6 resident at 24.5 KB LDS, ~75% occ),
// grid-stride over nodes -> ~65 nodes per W2 load, staging 400 -> 24 MB.
// Inner aggregate loop identical to the 73 us R14 version.

__global__ void k_agg_tf(const int* __restrict__ offs, const int* __restrict__ srcs,
                         const unsigned short* __restrict__ featS,   // L1 fp8 table
                         const float* __restrict__ asrc, const float* __restrict__ adst,
                         const float* __restrict__ bias,             // b1
                         const float* __restrict__ W2,
                         const float* __restrict__ as2, const float* __restrict__ ad2,
                         unsigned char* __restrict__ feat8B,
                         float* __restrict__ asrc2, float* __restrict__ adst2, int N){
  __shared__ float2 lwh[4][4][66];         // [wave][head][edge slot(+pad)]
  __shared__ float sW2[HC*HC];             // 16 KB, staged ONCE per block
  int t = threadIdx.x, lane = t & 63, wid = t >> 6;
  for (int i = t; i < HC*HC; i += blockDim.x) sW2[i] = W2[i];
  __syncthreads();
  int cl = lane & 31, half = lane >> 5, h2i = cl >> 3;
  float bia = bias[lane];
  float as_l = as2[lane], ad_l = ad2[lane];
  const float2* lp = &lwh[wid][h2i][half];
  int stride = gridDim.x*4;
  for (int n = blockIdx.x*4 + wid; n < N; n += stride){
    const float4 adv = *(const float4*)(adst + (size_t)n*4);
    int beg = offs[n], end = offs[n+1];
    float2 acc = make_float2(0.f, 0.f);
    float den = 0.f;
    int i0 = beg + lane;
    int sv = (i0 < end) ? srcs[i0] : 0;
    float4 av = *(const float4*)(asrc + (size_t)sv*4);
    for (int j0 = beg; j0 < end; j0 += 64){
      int m = end - j0; if (m > 64) m = 64;
      float z = (lane < m) ? 1.f : 0.f;
      float e0 = av.x + adv.x; e0 = (e0>0.f)?e0:0.2f*e0;
      float e1 = av.y + adv.y; e1 = (e1>0.f)?e1:0.2f*e1;
      float e2 = av.z + adv.z; e2 = (e2>0.f)?e2:0.2f*e2;
      float e3 = av.w + adv.w; e3 = (e3>0.f)?e3:0.2f*e3;
      float ob = __int_as_float(sv << 5);  // ushort row offset (row = 32 ushorts)
      lwh[wid][0][lane] = make_float2(z*__expf(e0), ob);
      lwh[wid][1][lane] = make_float2(z*__expf(e1), ob);
      lwh[wid][2][lane] = make_float2(z*__expf(e2), ob);
      lwh[wid][3][lane] = make_float2(z*__expf(e3), ob);
      int nj = j0 + 64;
      int svn = 0; float4 avn = av;
      if (nj < end){
        int i1 = nj + lane;
        svn = (i1 < end) ? srcs[i1] : 0;
        avn = *(const float4*)(asrc + (size_t)svn*4);
      }
      #pragma unroll 8
      for (int jj = 0; jj < m; jj += 2){
        float2 rec = lp[jj];
        unsigned idx = (unsigned)__float_as_int(rec.y) | (unsigned)cl;
        unsigned short d = featS[idx];
        f2_t f2 = __builtin_amdgcn_cvt_pk_f32_fp8((int)d, false);
        acc.x = fmaf(rec.x, f2.x, acc.x);
        acc.y = fmaf(rec.x, f2.y, acc.y);
        den += rec.x;
      }
      sv = svn; av = avn;
    }
    acc.x += __shfl_xor(acc.x, 32);
    acc.y += __shfl_xor(acc.y, 32);
    den   += __shfl_xor(den, 32);
    float vx = __shfl(acc.x, lane >> 1);
    float vy = __shfl(acc.y, lane >> 1);
    float r = ((lane & 1) ? vy : vx)/den + bia;
    r = (r > 0.f) ? r : expm1f(r);         // elu -> h1[lane], fp32
    // ---- fused transform-2: h2[lane] = sum_k h1[k] * W2[k][lane] ----
    float a2 = 0.f;
    #pragma unroll
    for (int k = 0; k < HC; k++){
      float hk = __shfl(r, k);             // uniform idx -> readlane broadcast
      a2 = fmaf(hk, sW2[k*HC + lane], a2);
    }
    feat8B[((size_t)n << 6) + lane] = f2fp8(a2);
    float ps = a2*as_l, pd = a2*ad_l;
    #pragma unroll
    for (int d = 1; d < 16; d <<= 1){ ps += __shfl_xor(ps, d); pd += __shfl_xor(pd, d); }
    if ((lane & 15) == 0){
      asrc2[n*4 + (lane>>4)] = ps;
      adst2[n*4 + (lane>>4)] = pd;
    }
  }
}

// ---- layer-2 aggregate + pool (v8 FINAL path, unchanged) ---------------

__global__ void k_agg_pool(const int* __restrict__ offs, const int* __restrict__ srcs,
                           const unsigned short* __restrict__ featS,  // L2 fp8 table
                           const float* __restrict__ asrc, const float* __restrict__ adst,
                           const float* __restrict__ bias,            // b2
                           const int* __restrict__ batch,
                           float* __restrict__ pooled, int N){
  __shared__ float2 lwh[4][4][66];
  __shared__ float red[4][HC];
  int t = threadIdx.x, lane = t & 63, wid = t >> 6;
  int n = blockIdx.x*4 + wid;
  bool active = (n < N);
  int ns = active ? n : (N-1);
  int cl = lane & 31, half = lane >> 5, h2i = cl >> 3;
  const float4 adv = *(const float4*)(adst + (size_t)ns*4);
  int beg = offs[ns], end = offs[ns+1];
  float2 acc = make_float2(0.f, 0.f);
  float den = 0.f;
  const float2* lp = &lwh[wid][h2i][half];
  int i0 = beg + lane;
  int sv = (i0 < end) ? srcs[i0] : 0;
  float4 av = *(const float4*)(asrc + (size_t)sv*4);
  for (int j0 = beg; j0 < end; j0 += 64){
    int m = end - j0; if (m > 64) m = 64;
    float z = (lane < m) ? 1.f : 0.f;
    float e0 = av.x + adv.x; e0 = (e0>0.f)?e0:0.2f*e0;
    float e1 = av.y + adv.y; e1 = (e1>0.f)?e1:0.2f*e1;
    float e2 = av.z + adv.z; e2 = (e2>0.f)?e2:0.2f*e2;
    float e3 = av.w + adv.w; e3 = (e3>0.f)?e3:0.2f*e3;
    float ob = __int_as_float(sv << 5);
    lwh[wid][0][lane] = make_float2(z*__expf(e0), ob);
    lwh[wid][1][lane] = make_float2(z*__expf(e1), ob);
    lwh[wid][2][lane] = make_float2(z*__expf(e2), ob);
    lwh[wid][3][lane] = make_float2(z*__expf(e3), ob);
    int nj = j0 + 64;
    int svn = 0; float4 avn = av;
    if (nj < end){
      int i1 = nj + lane;
      svn = (i1 < end) ? srcs[i1] : 0;
      avn = *(const float4*)(asrc + (size_t)svn*4);
    }
    #pragma unroll 8
    for (int jj = 0; jj < m; jj += 2){
      float2 rec = lp[jj];
      unsigned idx = (unsigned)__float_as_int(rec.y) | (unsigned)cl;
      unsigned short d = featS[idx];
      f2_t f2 = __builtin_amdgcn_cvt_pk_f32_fp8((int)d, false);
      acc.x = fmaf(rec.x, f2.x, acc.x);
      acc.y = fmaf(rec.x, f2.y, acc.y);
      den += rec.x;
    }
    sv = svn; av = avn;
  }
  acc.x += __shfl_xor(acc.x, 32);
  acc.y += __shfl_xor(acc.y, 32);
  den   += __shfl_xor(den, 32);
  float vx = __shfl(acc.x, lane >> 1);
  float vy = __shfl(acc.y, lane >> 1);
  float r = ((lane & 1) ? vy : vx)/den + bias[lane];
  r = (r > 0.f) ? r : expm1f(r);           // elu
  red[wid][lane] = active ? r : 0.f;
  __syncthreads();
  if (wid == 0){
    int n0 = blockIdx.x*4;
    int g0 = batch[min(n0, N-1)];
    int g3 = batch[min(n0+3, N-1)];
    float s4 = red[0][lane] + red[1][lane] + red[2][lane] + red[3][lane];
    if (g0 == g3){                         // fast path (~96% of blocks)
      atomicAdd(&pooled[(size_t)g0*HC + lane], s4);
    } else {
      for (int w2 = 0; w2 < 4; w2++){
        int nw = n0 + w2;
        if (nw < N) atomicAdd(&pooled[(size_t)batch[nw]*HC + lane], red[w2][lane]);
      }
    }
  }
}

// ---- head: mean-pool already summed; MLPs. fp32 output -----------------

__global__ void k_final(const float* __restrict__ pooled, const int* __restrict__ gcnt,
                        const float* __restrict__ guid,
                        const float* __restrict__ Wg, const float* __restrict__ bg,
                        const float* __restrict__ Wu, const float* __restrict__ bu,
                        const float* __restrict__ Wo, const float* __restrict__ bo,
                        float* __restrict__ outp, int G){
  __shared__ float sWg[HC*16], sWo[16*7], sbg[16], sWu[16], sbu[16], sbo[7];
  int t = threadIdx.x;
  for (int i = t; i < HC*16; i += blockDim.x) sWg[i] = Wg[i];
  for (int i = t; i < 16*7;  i += blockDim.x) sWo[i] = Wo[i];
  if (t < 16){ sbg[t] = bg[t]; sWu[t] = Wu[t]; sbu[t] = bu[t]; }
  if (t < 7) sbo[t] = bo[t];
  __syncthreads();
  int g = blockIdx.x*blockDim.x + t;
  if (g >= G) return;
  float inv = 1.f / fmaxf((float)gcnt[g], 1.f);
  float v[16];
  #pragma unroll
  for (int j = 0; j < 16; j++) v[j] = sbg[j];
  for (int c = 0; c < HC; c++){
    float pc = pooled[g*HC + c] * inv;
    #pragma unroll
    for (int j = 0; j < 16; j++) v[j] = fmaf(pc, sWg[c*16 + j], v[j]);
  }
  float gd = guid[g];
  #pragma unroll
  for (int j = 0; j < 16; j++){
    float u = fmaf(gd, sWu[j], sbu[j]);
    v[j] += (u > 0.f) ? u : 0.f;
  }
  #pragma unroll
  for (int k = 0; k < 7; k++){
    float o = sbo[k];
    #pragma unroll
    for (int j = 0; j < 16; j++) o = fmaf(v[j], sWo[j*7 + k], o);
    outp[g*7 + k] = o;
  }
}

// ---- launch ------------------------------------------------------------

extern "C" void kernel_launch(void* const* d_in, const int* in_sizes, int n_in,
                              void* d_out, int out_size, void* d_ws, size_t ws_size,
                              hipStream_t stream){
  const float* x    = (const float*)d_in[0];
  const int*   edge = (const int*)d_in[1];
  const int*   batch= (const int*)d_in[2];
  const float* guid = (const float*)d_in[3];
  const float* W1   = (const float*)d_in[4];
  const float* as1  = (const float*)d_in[5];
  const float* ad1  = (const float*)d_in[6];
  const float* b1   = (const float*)d_in[7];
  const float* W2   = (const float*)d_in[8];
  const float* as2  = (const float*)d_in[9];
  const float* ad2  = (const float*)d_in[10];
  const float* b2   = (const float*)d_in[11];
  const float* Wg   = (const float*)d_in[12];
  const float* bg   = (const float*)d_in[13];
  const float* Wu   = (const float*)d_in[14];
  const float* bu   = (const float*)d_in[15];
  const float* Wo   = (const float*)d_in[16];
  const float* bo   = (const float*)d_in[17];

  const int N = in_sizes[0] / DIN;
  const int E = in_sizes[1] / 2;
  const int G = in_sizes[3];
  const int NB = (N + NPB - 1) >> 9;

  char* p = (char*)d_ws;
  auto alloc = [&](size_t nbytes)->void*{
    void* r = (void*)p;
    p += ((nbytes + 255) & ~(size_t)255);
    return r;
  };
  char*  zstart = p;                       // bcur|gcnt|pooled zeroed together
  int*   bcur   = (int*)  alloc(1024*4);
  int*   gcnt   = (int*)  alloc((size_t)G*4);
  float* pooled = (float*)alloc((size_t)G*HC*4);
  size_t zbytes = (size_t)(p - zstart);
  int*   offs   = (int*)  alloc((size_t)(N+1)*4);
  int*   srcs   = (int*)  alloc(((size_t)E + N)*4);
  unsigned char* feat8A = (unsigned char*)alloc((size_t)N*HC);  // L1 fp8 table
  unsigned char* feat8B = (unsigned char*)alloc((size_t)N*HC);  // L2 fp8 table
  float* asrc1  = (float*)alloc((size_t)N*4*4);
  float* adst1  = (float*)alloc((size_t)N*4*4);
  float* asrc2  = (float*)alloc((size_t)N*4*4);
  float* adst2  = (float*)alloc((size_t)N*4*4);
  unsigned* buf = (unsigned*)alloc((size_t)NB*CAP*4);
  (void)ws_size; (void)n_in; (void)out_size;

  hipMemsetAsync(zstart, 0, zbytes, stream);

  const int tpb = 256;
  const int SB  = 256;                     // scatter blocks
  const int TB  = 1024;                    // transform blocks
  // fused: scatter edge->buf  ||  tf1 x->feat8A + asrc1/adst1
  k_scatter_tf<DIN><<<SB + TB, tpb, 0, stream>>>(
      edge, E, NB, bcur, buf, SB, x, W1, as1, ad1, feat8A, asrc1, adst1, N, TB);
  k_bbuild<<<NB, NPB, 0, stream>>>(buf, bcur, batch, NB, N, offs, srcs, gcnt);

  // layer 1 aggregate + fused layer-2 transform (grid-stride, 1536 blocks)
  k_agg_tf<<<1536, tpb, 0, stream>>>(offs, srcs, (const unsigned short*)feat8A,
                                     asrc1, adst1, b1, W2, as2, ad2,
                                     feat8B, asrc2, adst2, N);
  // layer 2 aggregate + pool (1 node per wave)
  const int nb = (N + 3) / 4;
  k_agg_pool<<<nb, tpb, 0, stream>>>(offs, srcs, (const unsigned short*)feat8B,
                                     asrc2, adst2, b2, batch, pooled, N);

  k_final<<<(G+255)/256, 256, 0, stream>>>(pooled, gcnt, guid, Wg, bg, Wu, bu, Wo, bo,
                                           (float*)d_out, G);
}

// Round 17
// 381.326 us; speedup vs baseline: 1.4143x; 1.4143x over previous
//
#include <hip/hip_runtime.h>
#include <hip/hip_bf16.h>

#define DIN 32
#define HC  64    // H*C
#define NPB 512   // nodes per bucket (dst >> 9)
#define CAP 18432 // fixed bucket capacity: E/NB=16384 expected, sigma~127 -> 16 sigma

using bf = __hip_bfloat16;
typedef float f2_t __attribute__((ext_vector_type(2)));
static __device__ __forceinline__ unsigned char f2fp8(float v){
  return (unsigned char)__builtin_amdgcn_cvt_pk_fp8_f32(v, v, 0, false);
}

// ---- fused: bucket-scatter (blocks < SB) || transform layer-1 ----------
// tf1: feat8A = fp8(x@W1) (gathered rows 64 B); asrc/adst from fp32 acc
// BEFORE quantization -> attention logits exact. (R13-proven fusion.)

template<int K>
__global__ void k_scatter_tf(const int* __restrict__ edge, int E, int NB,
                             int* __restrict__ bcur, unsigned* __restrict__ buf,
                             int SB,
                             const float* __restrict__ xin,
                             const float* __restrict__ W,
                             const float* __restrict__ a_s,
                             const float* __restrict__ a_d,
                             unsigned char* __restrict__ feat8,
                             float* __restrict__ asrc, float* __restrict__ adst, int N,
                             int TB){
  __shared__ int lcnt[1024];
  __shared__ int lcur[1024];
  int t = threadIdx.x;
  if ((int)blockIdx.x < SB){               // ---- scatter half ----
    int chunk = (E + SB - 1) / SB;
    int beg = blockIdx.x*chunk, end = min(E, beg + chunk);
    for (int i = t; i < NB; i += blockDim.x) lcnt[i] = 0;
    __syncthreads();
    for (int i = beg + t; i < end; i += blockDim.x)
      atomicAdd(&lcnt[edge[E + i] >> 9], 1);
    __syncthreads();
    for (int i = t; i < NB; i += blockDim.x){
      int c = lcnt[i];
      lcur[i] = i*CAP + (c ? atomicAdd(&bcur[i], c) : 0);
    }
    __syncthreads();
    for (int i = beg + t; i < end; i += blockDim.x){
      int sN = edge[i], d = edge[E + i];
      int pos = atomicAdd(&lcur[d >> 9], 1);
      buf[pos] = ((unsigned)sN << 9) | (unsigned)(d & 511);
    }
    return;
  }
  // ---- transform half (W column in VGPRs, x same-addr broadcast)
  int lane = t & 63, wid = t >> 6;
  float wreg[K];
  #pragma unroll
  for (int k = 0; k < K; k++) wreg[k] = W[k*HC + lane];
  float as_l = a_s[lane], ad_l = a_d[lane];
  int gw = (blockIdx.x - SB)*4 + wid;
  int nw = TB*4;
  for (int n = gw; n < N; n += nw){
    float acc = 0.f;
    const float* xr = xin + (size_t)n*K;
    #pragma unroll
    for (int k = 0; k < K; k += 4){
      float4 xv = *(const float4*)(xr + k);              // same-addr broadcast
      acc = fmaf(xv.x, wreg[k+0], acc);
      acc = fmaf(xv.y, wreg[k+1], acc);
      acc = fmaf(xv.z, wreg[k+2], acc);
      acc = fmaf(xv.w, wreg[k+3], acc);
    }
    feat8[((size_t)n << 6) + lane] = f2fp8(acc);         // 1 B/lane, 64 B row
    float ps = acc*as_l, pd = acc*ad_l;                  // fp32: logits exact
    #pragma unroll
    for (int d = 1; d < 16; d <<= 1){ ps += __shfl_xor(ps, d); pd += __shfl_xor(pd, d); }
    if ((lane & 15) == 0){
      asrc[n*4 + (lane>>4)] = ps;
      adst[n*4 + (lane>>4)] = pd;
    }
  }
}

// ---- bucket CSR build: 1024 thr/block (R16 post-mortem: 196x512 = <40%
// of wave slots, two serial passes over ~17k edges each). 1024 threads
// halves per-thread work. bscan folded in as a pair tree-reduce (each
// block needs only sum(fills[0..b)) and the total) -- dispatch + gap gone.

__global__ void k_bbuild(const unsigned* __restrict__ buf, const int* __restrict__ bcur,
                         const int* __restrict__ batch,
                         int NB, int N, int* __restrict__ offs, int* __restrict__ srcs,
                         int* __restrict__ gcnt){
  __shared__ int2 rd[1024];
  __shared__ int s[NPB];
  __shared__ int cur[NPB];
  int b = blockIdx.x, t = threadIdx.x;
  // ---- folded scan: sb = sum of prior bucket fills (pair reduce) ----
  int v = (t < NB) ? min(bcur[t], CAP) : 0;
  rd[t] = make_int2((t < b) ? v : 0, v);
  __syncthreads();
  for (int d = 512; d > 0; d >>= 1){
    if (t < d){ rd[t].x += rd[t+d].x; rd[t].y += rd[t+d].y; }
    __syncthreads();
  }
  int sb = rd[0].x + b*NPB;                // + self-loops of prior buckets
  if (b == 0 && t == 0) offs[N] = rd[0].y + N;
  // ---- local CSR ----
  int base = b << 9;
  int nn = min(NPB, N - base);
  int sbeg = b*CAP;
  int send = sbeg + min(bcur[b], CAP);
  if (t < NPB) s[t] = (t < nn) ? 1 : 0;    // self-loop seed
  __syncthreads();
  for (int i = sbeg + t; i < send; i += 1024)
    atomicAdd(&s[buf[i] & 511u], 1);
  __syncthreads();
  int c0 = (t < NPB) ? s[t] : 0;
  __syncthreads();
  for (int d = 1; d < NPB; d <<= 1){
    int w = (t < NPB && t >= d) ? s[t-d] : 0;
    __syncthreads();
    if (t < NPB) s[t] += w;
    __syncthreads();
  }
  if (t < nn){
    int start = s[t] - c0;
    offs[base + t] = sb + start;
    srcs[sb + start] = base + t;           // self-loop
    cur[t] = start + 1;
    atomicAdd(&gcnt[batch[base + t]], 1);  // graph node count
  }
  __syncthreads();
  for (int i = sbeg + t; i < send; i += 1024){
    unsigned u = buf[i];
    int pos = atomicAdd(&cur[u & 511u], 1);
    srcs[sb + pos] = (int)(u >> 9);
  }
}

// transform layer 2: bf16 h1 rows in, fp8 feat out; logits from fp32.
template<int K>
__global__ void k_transform(const bf* __restrict__ xin,
                            const float* __restrict__ W,
                            const float* __restrict__ a_s,
                            const float* __restrict__ a_d,
                            unsigned char* __restrict__ feat8,
                            float* __restrict__ asrc, float* __restrict__ adst, int N){
  int t = threadIdx.x, lane = t & 63, wid = t >> 6;
  float wreg[K];
  #pragma unroll
  for (int k = 0; k < K; k++) wreg[k] = W[k*HC + lane];
  float as_l = a_s[lane], ad_l = a_d[lane];
  int gw = blockIdx.x*4 + wid;
  int nw = gridDim.x*4;
  for (int n = gw; n < N; n += nw){
    float acc = 0.f;
    const bf* xr = xin + (size_t)n*K;
    #pragma unroll
    for (int k = 0; k < K; k += 8){
      uint4 d = *(const uint4*)(xr + k);                 // same-addr broadcast
      acc = fmaf(__int_as_float((int)(d.x << 16)),         wreg[k+0], acc);
      acc = fmaf(__int_as_float((int)(d.x & 0xffff0000u)), wreg[k+1], acc);
      acc = fmaf(__int_as_float((int)(d.y << 16)),         wreg[k+2], acc);
      acc = fmaf(__int_as_float((int)(d.y & 0xffff0000u)), wreg[k+3], acc);
      acc = fmaf(__int_as_float((int)(d.z << 16)),         wreg[k+4], acc);
      acc = fmaf(__int_as_float((int)(d.z & 0xffff0000u)), wreg[k+5], acc);
      acc = fmaf(__int_as_float((int)(d.w << 16)),         wreg[k+6], acc);
      acc = fmaf(__int_as_float((int)(d.w & 0xffff0000u)), wreg[k+7], acc);
    }
    feat8[((size_t)n << 6) + lane] = f2fp8(acc);
    float ps = acc*as_l, pd = acc*ad_l;
    #pragma unroll
    for (int d = 1; d < 16; d <<= 1){ ps += __shfl_xor(ps, d); pd += __shfl_xor(pd, d); }
    if ((lane & 15) == 0){
      asrc[n*4 + (lane>>4)] = ps;
      adst[n*4 + (lane>>4)] = pd;
    }
  }
}

// ---- softmax-aggregate v8 (R14, measured 72.8 us) ----------------------
// fp8 gathers: 2 random 64-B segments per VMEM instr (R9 law). 2 B/lane
// epilogue stores. FINAL pools via block LDS combine. agg_tf fusion
// abandoned (R15: 189 us staging; R16: 263 us VGPR/occupancy).

template<bool FINAL>
__global__ void k_aggregate(const int* __restrict__ offs, const int* __restrict__ srcs,
                            const unsigned short* __restrict__ featS,
                            const float* __restrict__ asrc, const float* __restrict__ adst,
                            const float* __restrict__ bias,
                            bf* __restrict__ out,
                            const int* __restrict__ batch,
                            float* __restrict__ pooled, int N){
  __shared__ float2 lwh[4][4][66];         // [wave][head][edge slot(+pad)]
  __shared__ float red[4][HC];             // FINAL block combine
  int t = threadIdx.x, lane = t & 63, wid = t >> 6;
  int n = blockIdx.x*4 + wid;
  bool active = (n < N);
  if (!FINAL && !active) return;
  int ns = active ? n : (N-1);             // safe index for inactive tail waves
  int cl = lane & 31, half = lane >> 5, h2i = cl >> 3;
  const float4 adv = *(const float4*)(adst + (size_t)ns*4);
  int beg = offs[ns], end = offs[ns+1];
  float2 acc = make_float2(0.f, 0.f);
  float den = 0.f;
  const float2* lp = &lwh[wid][h2i][half];
  int i0 = beg + lane;
  int sv = (i0 < end) ? srcs[i0] : 0;
  float4 av = *(const float4*)(asrc + (size_t)sv*4);
  for (int j0 = beg; j0 < end; j0 += 64){
    int m = end - j0; if (m > 64) m = 64;
    float z = (lane < m) ? 1.f : 0.f;
    float e0 = av.x + adv.x; e0 = (e0>0.f)?e0:0.2f*e0;
    float e1 = av.y + adv.y; e1 = (e1>0.f)?e1:0.2f*e1;
    float e2 = av.z + adv.z; e2 = (e2>0.f)?e2:0.2f*e2;
    float e3 = av.w + adv.w; e3 = (e3>0.f)?e3:0.2f*e3;
    float ob = __int_as_float(sv << 5);    // ushort row offset (row = 32 ushorts)
    lwh[wid][0][lane] = make_float2(z*__expf(e0), ob);
    lwh[wid][1][lane] = make_float2(z*__expf(e1), ob);
    lwh[wid][2][lane] = make_float2(z*__expf(e2), ob);
    lwh[wid][3][lane] = make_float2(z*__expf(e3), ob);
    int nj = j0 + 64;
    int svn = 0; float4 avn = av;
    if (nj < end){
      int i1 = nj + lane;
      svn = (i1 < end) ? srcs[i1] : 0;
      avn = *(const float4*)(asrc + (size_t)svn*4);
    }
    #pragma unroll 8
    for (int jj = 0; jj < m; jj += 2){
      float2 rec = lp[jj];                 // (w for my head, row offset bits)
      unsigned idx = (unsigned)__float_as_int(rec.y) | (unsigned)cl;
      unsigned short d = featS[idx];       // 2 fp8 channels of my edge's row
      f2_t f2 = __builtin_amdgcn_cvt_pk_f32_fp8((int)d, false);
      acc.x = fmaf(rec.x, f2.x, acc.x);
      acc.y = fmaf(rec.x, f2.y, acc.y);
      den += rec.x;
    }
    sv = svn; av = avn;
  }
  acc.x += __shfl_xor(acc.x, 32);
  acc.y += __shfl_xor(acc.y, 32);
  den   += __shfl_xor(den, 32);            // all 64 lanes now hold totals
  float vx = __shfl(acc.x, lane >> 1);
  float vy = __shfl(acc.y, lane >> 1);
  float r = ((lane & 1) ? vy : vx)/den + bias[lane];
  r = (r > 0.f) ? r : expm1f(r);           // elu
  if (FINAL){
    red[wid][lane] = active ? r : 0.f;
    __syncthreads();
    if (wid == 0){
      int n0 = blockIdx.x*4;
      int g0 = batch[min(n0, N-1)];
      int g3 = batch[min(n0+3, N-1)];
      float s4 = red[0][lane] + red[1][lane] + red[2][lane] + red[3][lane];
      if (g0 == g3){                       // fast path (~96% of blocks)
        atomicAdd(&pooled[(size_t)g0*HC + lane], s4);
      } else {
        for (int w2 = 0; w2 < 4; w2++){
          int nw = n0 + w2;
          if (nw < N) atomicAdd(&pooled[(size_t)batch[nw]*HC + lane], red[w2][lane]);
        }
      }
    }
  } else {
    out[((size_t)n << 6) + lane] = __float2bfloat16(r);   // 2 B/lane store
  }
}

// ---- head: mean-pool already summed; MLPs. fp32 output -----------------

__global__ void k_final(const float* __restrict__ pooled, const int* __restrict__ gcnt,
                        const float* __restrict__ guid,
                        const float* __restrict__ Wg, const float* __restrict__ bg,
                        const float* __restrict__ Wu, const float* __restrict__ bu,
                        const float* __restrict__ Wo, const float* __restrict__ bo,
                        float* __restrict__ outp, int G){
  __shared__ float sWg[HC*16], sWo[16*7], sbg[16], sWu[16], sbu[16], sbo[7];
  int t = threadIdx.x;
  for (int i = t; i < HC*16; i += blockDim.x) sWg[i] = Wg[i];
  for (int i = t; i < 16*7;  i += blockDim.x) sWo[i] = Wo[i];
  if (t < 16){ sbg[t] = bg[t]; sWu[t] = Wu[t]; sbu[t] = bu[t]; }
  if (t < 7) sbo[t] = bo[t];
  __syncthreads();
  int g = blockIdx.x*blockDim.x + t;
  if (g >= G) return;
  float inv = 1.f / fmaxf((float)gcnt[g], 1.f);
  float v[16];
  #pragma unroll
  for (int j = 0; j < 16; j++) v[j] = sbg[j];
  for (int c = 0; c < HC; c++){
    float pc = pooled[g*HC + c] * inv;
    #pragma unroll
    for (int j = 0; j < 16; j++) v[j] = fmaf(pc, sWg[c*16 + j], v[j]);
  }
  float gd = guid[g];
  #pragma unroll
  for (int j = 0; j < 16; j++){
    float u = fmaf(gd, sWu[j], sbu[j]);
    v[j] += (u > 0.f) ? u : 0.f;
  }
  #pragma unroll
  for (int k = 0; k < 7; k++){
    float o = sbo[k];
    #pragma unroll
    for (int j = 0; j < 16; j++) o = fmaf(v[j], sWo[j*7 + k], o);
    outp[g*7 + k] = o;
  }
}

// ---- launch ------------------------------------------------------------

extern "C" void kernel_launch(void* const* d_in, const int* in_sizes, int n_in,
                              void* d_out, int out_size, void* d_ws, size_t ws_size,
                              hipStream_t stream){
  const float* x    = (const float*)d_in[0];
  const int*   edge = (const int*)d_in[1];
  const int*   batch= (const int*)d_in[2];
  const float* guid = (const float*)d_in[3];
  const float* W1   = (const float*)d_in[4];
  const float* as1  = (const float*)d_in[5];
  const float* ad1  = (const float*)d_in[6];
  const float* b1   = (const float*)d_in[7];
  const float* W2   = (const float*)d_in[8];
  const float* as2  = (const float*)d_in[9];
  const float* ad2  = (const float*)d_in[10];
  const float* b2   = (const float*)d_in[11];
  const float* Wg   = (const float*)d_in[12];
  const float* bg   = (const float*)d_in[13];
  const float* Wu   = (const float*)d_in[14];
  const float* bu   = (const float*)d_in[15];
  const float* Wo   = (const float*)d_in[16];
  const float* bo   = (const float*)d_in[17];

  const int N = in_sizes[0] / DIN;
  const int E = in_sizes[1] / 2;
  const int G = in_sizes[3];
  const int NB = (N + NPB - 1) >> 9;

  char* p = (char*)d_ws;
  auto alloc = [&](size_t nbytes)->void*{
    void* r = (void*)p;
    p += ((nbytes + 255) & ~(size_t)255);
    return r;
  };
  char*  zstart = p;                       // bcur|gcnt|pooled zeroed together
  int*   bcur   = (int*)  alloc(1024*4);
  int*   gcnt   = (int*)  alloc((size_t)G*4);
  float* pooled = (float*)alloc((size_t)G*HC*4);
  size_t zbytes = (size_t)(p - zstart);
  int*   offs   = (int*)  alloc((size_t)(N+1)*4);
  int*   srcs   = (int*)  alloc(((size_t)E + N)*4);
  unsigned char* feat8A = (unsigned char*)alloc((size_t)N*HC);  // L1 fp8 table
  unsigned char* feat8B = (unsigned char*)alloc((size_t)N*HC);  // L2 fp8 table
  float* asrc   = (float*)alloc((size_t)N*4*4);
  float* adst   = (float*)alloc((size_t)N*4*4);
  size_t featBSz = (size_t)N*HC*2;         // bf16 h1
  size_t bufSz   = (size_t)NB*CAP*4;       // pair buffer (fixed-capacity slots)
  if (bufSz > featBSz) featBSz = bufSz;
  bf*    featB  = (bf*)   alloc(featBSz);  // buf aliases (dead before agg1 writes)
  unsigned* buf = (unsigned*)featB;
  (void)ws_size; (void)n_in; (void)out_size;

  hipMemsetAsync(zstart, 0, zbytes, stream);

  const int tpb = 256;
  const int SB  = 256;                     // scatter blocks
  const int TB  = 1024;                    // transform blocks
  // fused: scatter edge->buf  ||  tf1 x->feat8A + asrc/adst
  k_scatter_tf<DIN><<<SB + TB, tpb, 0, stream>>>(
      edge, E, NB, bcur, buf, SB, x, W1, as1, ad1, feat8A, asrc, adst, N, TB);
  // CSR build, folded scan, 1024 threads/block
  k_bbuild<<<NB, 1024, 0, stream>>>(buf, bcur, batch, NB, N, offs, srcs, gcnt);

  const int nb = (N + 3) / 4;              // aggregates: 1 node per wave
  // layer 1: aggregate feat8A -> featB (bf16 h1; overwrites dead buf)
  k_aggregate<false><<<nb, tpb, 0, stream>>>(offs, srcs, (const unsigned short*)feat8A,
                                             asrc, adst, b1, featB, batch, pooled, N);
  // layer 2: featB -> feat8B ; aggregate feat8B -> pooled
  k_transform<HC><<<TB, tpb, 0, stream>>>(featB, W2, as2, ad2, feat8B, asrc, adst, N);
  k_aggregate<true><<<nb, tpb, 0, stream>>>(offs, srcs, (const unsigned short*)feat8B,
                                            asrc, adst, b2, nullptr, batch, pooled, N);

  k_final<<<(G+255)/256, 256, 0, stream>>>(pooled, gcnt, guid, Wg, bg, Wu, bu, Wo, bo,
                                           (float*)d_out, G);
}